// Round 8
// baseline (437.903 us; speedup 1.0000x reference)
//
#include <hip/hip_runtime.h>

#define B_ 16
#define D_ 768
#define N_ 4096
#define Q_ 128

typedef __attribute__((ext_vector_type(4))) float f32x4;
typedef __attribute__((ext_vector_type(8))) short short8;
typedef __attribute__((ext_vector_type(4))) short sv4;

__device__ __forceinline__ unsigned short f2bf(float f) {
  union { float f; unsigned u; } x; x.f = f;
  unsigned u = x.u;
  unsigned r = u + 0x7fffu + ((u >> 16) & 1u);
  return (unsigned short)(r >> 16);
}
__device__ __forceinline__ float bf2f(unsigned short h) {
  union { unsigned u; float f; } x; x.u = ((unsigned)h) << 16;
  return x.f;
}

// ---- prep: z=0 cast Wk, z=1 cast Wv, z=2 transpose+cast Wq, z=3 text cast+entropy ----
__global__ __launch_bounds__(256) void prep_kernel(
    const float* __restrict__ Wk, const float* __restrict__ Wv,
    const float* __restrict__ Wq, const float* __restrict__ text,
    unsigned short* __restrict__ Wkb, unsigned short* __restrict__ Wvb,
    unsigned short* __restrict__ WqTb, unsigned short* __restrict__ textb,
    float* __restrict__ ent_t) {
  __shared__ float tile[32][33];
  const int z = blockIdx.z;
  const int t = threadIdx.x;
  if (z <= 1) {
    const float* src = z ? Wv : Wk;
    unsigned short* dst = z ? Wvb : Wkb;
    int i = (blockIdx.y * 24 + blockIdx.x) * 256 + t;  // 576*256 = 768*768/4
    float4 v = ((const float4*)src)[i];
    ushort4 o;
    o.x = f2bf(v.x); o.y = f2bf(v.y); o.z = f2bf(v.z); o.w = f2bf(v.w);
    ((ushort4*)dst)[i] = o;
  } else if (z == 2) {
    int bx = blockIdx.x * 32, by = blockIdx.y * 32;
    int tx = t & 31, ty = t >> 5;
    #pragma unroll
    for (int i = 0; i < 32; i += 8)
      tile[ty + i][tx] = Wq[(size_t)(by + ty + i) * D_ + bx + tx];
    __syncthreads();
    #pragma unroll
    for (int i = 0; i < 32; i += 8)
      WqTb[(size_t)(bx + ty + i) * D_ + by + tx] = f2bf(tile[tx][ty + i]);
  } else {
    // text: cast fp32->bf16 + per-row softmax-entropy; 512 of 576 blocks used
    int idx = blockIdx.y * 24 + blockIdx.x;
    if (idx >= 512) return;
    int row = idx * 4 + (t >> 6);
    int lane = t & 63;
    const float4* src = (const float4*)(text + (size_t)row * D_);
    ushort4* dst = (ushort4*)(textb + (size_t)row * D_);
    float s = 0.f, tt = 0.f;
    #pragma unroll
    for (int j = 0; j < 3; j++) {
      float4 v = src[lane + 64 * j];
      float e0 = __expf(v.x), e1 = __expf(v.y), e2 = __expf(v.z), e3 = __expf(v.w);
      s += (e0 + e1) + (e2 + e3);
      tt += v.x * e0 + v.y * e1;
      tt += v.z * e2 + v.w * e3;
      ushort4 o;
      o.x = f2bf(v.x); o.y = f2bf(v.y); o.z = f2bf(v.z); o.w = f2bf(v.w);
      dst[lane + 64 * j] = o;
    }
    #pragma unroll
    for (int off = 32; off; off >>= 1) {
      s += __shfl_xor(s, off);
      tt += __shfl_xor(tt, off);
    }
    if (lane == 0) ent_t[row] = __logf(s) - tt / s;  // m + log(sum e^{x-m}) - E_p[x]
  }
}

// ---------------- merged k (+bk) and vT (+bv, transposed store) GEMM --------------------
__global__ __launch_bounds__(256) void gemm_kvT_kernel(
    const unsigned short* __restrict__ A, const unsigned short* __restrict__ Wkb,
    const float* __restrict__ bk, unsigned short* __restrict__ kb,
    const unsigned short* __restrict__ Wvb, const float* __restrict__ bv,
    unsigned short* __restrict__ vTb) {
  constexpr int LDA = 72;
  __shared__ unsigned short As[64 * LDA];
  __shared__ unsigned short Bs[64 * LDA];
  const bool isV = blockIdx.y >= 12;
  const unsigned short* Bm = isV ? Wvb : Wkb;
  const float* bias = isV ? bv : bk;
  unsigned short* C = isV ? vTb : kb;
  int m0 = blockIdx.x * 64, n0 = (isV ? blockIdx.y - 12 : blockIdx.y) * 64;
  int t = threadIdx.x, wave = t >> 6, lane = t & 63;
  int wm = (wave & 1) * 32, wn = (wave >> 1) * 32;
  int fl = lane & 15, fq = lane >> 4;
  f32x4 acc[2][2];
  #pragma unroll
  for (int i = 0; i < 2; i++)
    #pragma unroll
    for (int j = 0; j < 2; j++) acc[i][j] = {0.f, 0.f, 0.f, 0.f};
  for (int k0 = 0; k0 < D_; k0 += 64) {
    __syncthreads();
    #pragma unroll
    for (int i = 0; i < 2; i++) {
      int c = t + 256 * i;
      int sr = c >> 3, sc = (c & 7) * 8;
      *(uint4*)(As + sr * LDA + sc) = *(const uint4*)(A + (size_t)(m0 + sr) * D_ + k0 + sc);
      *(uint4*)(Bs + sr * LDA + sc) = *(const uint4*)(Bm + (size_t)(n0 + sr) * D_ + k0 + sc);
    }
    __syncthreads();
    #pragma unroll
    for (int ks = 0; ks < 2; ks++) {
      short8 afr[2], bfr[2];
      #pragma unroll
      for (int i = 0; i < 2; i++)
        afr[i] = *(const short8*)(As + (wm + i * 16 + fl) * LDA + ks * 32 + fq * 8);
      #pragma unroll
      for (int j = 0; j < 2; j++)
        bfr[j] = *(const short8*)(Bs + (wn + j * 16 + fl) * LDA + ks * 32 + fq * 8);
      #pragma unroll
      for (int i = 0; i < 2; i++)
        #pragma unroll
        for (int j = 0; j < 2; j++)
          acc[i][j] = __builtin_amdgcn_mfma_f32_16x16x32_bf16(afr[i], bfr[j], acc[i][j], 0, 0, 0);
    }
  }
  #pragma unroll
  for (int i = 0; i < 2; i++)
    #pragma unroll
    for (int j = 0; j < 2; j++) {
      int n = n0 + wn + j * 16 + fl;
      float bb = bias[n];
      #pragma unroll
      for (int r = 0; r < 4; r++) {
        int m = m0 + wm + i * 16 + fq * 4 + r;
        float val = acc[i][j][r] + bb;
        if (isV) {
          int bt = m >> 7, q = m & 127;
          C[((size_t)bt * D_ + n) * Q_ + q] = f2bf(val);
        } else {
          C[(size_t)m * D_ + n] = f2bf(val);
        }
      }
    }
}

// ---------------- merged kq GEMM (y<12) and skq bias_dot (y>=12) ------------------------
__global__ __launch_bounds__(256) void gemm_kq_bias_kernel(
    const unsigned short* __restrict__ kb, const unsigned short* __restrict__ WqTb,
    unsigned short* __restrict__ kqb, const float* __restrict__ bq,
    float* __restrict__ skq) {
  constexpr int LDA = 72;
  __shared__ unsigned short As[64 * LDA];
  __shared__ unsigned short Bs[64 * LDA];
  const int t = threadIdx.x;
  if (blockIdx.y >= 12) {
    int idx = (blockIdx.y - 12) * 32 + blockIdx.x;   // 0..511
    int row = idx * 4 + (t >> 6);
    int lane = t & 63;
    const unsigned short* kr = kb + (size_t)row * D_;
    float s = 0.f;
    for (int k = lane; k < D_; k += 64) s += bq[k] * bf2f(kr[k]);
    #pragma unroll
    for (int off = 32; off; off >>= 1) s += __shfl_xor(s, off);
    if (lane == 0) skq[row] = s;
    return;
  }
  int m0 = blockIdx.x * 64, n0 = blockIdx.y * 64;
  int wave = t >> 6, lane = t & 63;
  int wm = (wave & 1) * 32, wn = (wave >> 1) * 32;
  int fl = lane & 15, fq = lane >> 4;
  f32x4 acc[2][2];
  #pragma unroll
  for (int i = 0; i < 2; i++)
    #pragma unroll
    for (int j = 0; j < 2; j++) acc[i][j] = {0.f, 0.f, 0.f, 0.f};
  for (int k0 = 0; k0 < D_; k0 += 64) {
    __syncthreads();
    #pragma unroll
    for (int i = 0; i < 2; i++) {
      int c = t + 256 * i;
      int sr = c >> 3, sc = (c & 7) * 8;
      *(uint4*)(As + sr * LDA + sc) = *(const uint4*)(kb + (size_t)(m0 + sr) * D_ + k0 + sc);
      *(uint4*)(Bs + sr * LDA + sc) = *(const uint4*)(WqTb + (size_t)(n0 + sr) * D_ + k0 + sc);
    }
    __syncthreads();
    #pragma unroll
    for (int ks = 0; ks < 2; ks++) {
      short8 afr[2], bfr[2];
      #pragma unroll
      for (int i = 0; i < 2; i++)
        afr[i] = *(const short8*)(As + (wm + i * 16 + fl) * LDA + ks * 32 + fq * 8);
      #pragma unroll
      for (int j = 0; j < 2; j++)
        bfr[j] = *(const short8*)(Bs + (wn + j * 16 + fl) * LDA + ks * 32 + fq * 8);
      #pragma unroll
      for (int i = 0; i < 2; i++)
        #pragma unroll
        for (int j = 0; j < 2; j++)
          acc[i][j] = __builtin_amdgcn_mfma_f32_16x16x32_bf16(afr[i], bfr[j], acc[i][j], 0, 0, 0);
    }
  }
  #pragma unroll
  for (int i = 0; i < 2; i++)
    #pragma unroll
    for (int j = 0; j < 2; j++) {
      int n = n0 + wn + j * 16 + fl;
      #pragma unroll
      for (int r = 0; r < 4; r++) {
        int m = m0 + wm + i * 16 + fq * 4 + r;
        kqb[(size_t)m * D_ + n] = f2bf(acc[i][j][r]);
      }
    }
}

// ---------------- A1: S = vf*kq^T + inline visual entropy, 64-token blocks --------------
// vis staged via float4-along-n (16B/lane); S stored fragment-linear (16B/lane).
__global__ __launch_bounds__(256, 2) void attn_s_kernel(
    const float* __restrict__ vis,
    const unsigned short* __restrict__ kq,   // [B][Q][768] bf16
    float* __restrict__ S,                   // [1024 blocks][256 thr][32] fp32 fragment order
    float* __restrict__ ent_v)               // [B][4096]
{
  constexpr int LA = 68;
  constexpr int LB = 72;
  __shared__ unsigned short As[64 * LA];    //  8704 B
  __shared__ unsigned short Bs[128 * LB];   // 18432 B
  __shared__ float esh[512];                //  2048 B

  const int bb = blockIdx.x >> 6;
  const int n0 = (blockIdx.x & 63) * 64;
  const int t = threadIdx.x;
  const int wave = t >> 6, lane = t & 63;
  const int fl = lane & 15, fq = lane >> 4;
  const int wm = (wave & 1) * 32;   // token half (32 of 64)
  const int wq = (wave >> 1) * 64;  // q half

  const float* abase = vis + (size_t)bb * D_ * N_ + n0;
  const unsigned short* bbase = kq + (size_t)bb * Q_ * D_;

  f32x4 acc[2][4];
  #pragma unroll
  for (int i = 0; i < 2; i++)
    #pragma unroll
    for (int j = 0; j < 4; j++) acc[i][j] = {0.f, 0.f, 0.f, 0.f};

  // per-thread entropy partials for 4 fixed tokens (col4*4+j); no-max form (|v|<~6)
  const int col4 = t & 15;
  float es4[4] = {0.f, 0.f, 0.f, 0.f}, ets4[4] = {0.f, 0.f, 0.f, 0.f};

  for (int k0 = 0; k0 < D_; k0 += 64) {
    __syncthreads();
    // stage A: float4 along n (4 tokens/load), transpose to [tok][k] bf16 in LDS
    #pragma unroll
    for (int i = 0; i < 4; i++) {
      const int row = (t >> 4) + 16 * i;     // d within chunk
      const float4 v = *(const float4*)(abase + (size_t)(k0 + row) * N_ + col4 * 4);
      const float vv[4] = {v.x, v.y, v.z, v.w};
      #pragma unroll
      for (int j = 0; j < 4; j++) {
        const float e = __expf(vv[j]);
        es4[j] += e;
        ets4[j] += vv[j] * e;
        As[(col4 * 4 + j) * LA + row] = f2bf(vv[j]);
      }
    }
    // stage B: kq rows, contiguous k (128 q x 64 k)
    #pragma unroll
    for (int i = 0; i < 4; i++) {
      const int c = t + 256 * i;
      const int q = c >> 3, kc = (c & 7) * 8;
      const uint4 v = *(const uint4*)(bbase + (size_t)q * D_ + k0 + kc);
      *(uint4*)(Bs + q * LB + kc) = v;
    }
    __syncthreads();
    #pragma unroll
    for (int ks = 0; ks < 2; ks++) {
      short8 afr[2], bfr[4];
      #pragma unroll
      for (int i = 0; i < 2; i++) {
        const unsigned short* pa = As + (wm + i * 16 + fl) * LA + ks * 32 + fq * 8;
        sv4 lo = *(const sv4*)pa;
        sv4 hi = *(const sv4*)(pa + 4);
        afr[i] = __builtin_shufflevector(lo, hi, 0, 1, 2, 3, 4, 5, 6, 7);
      }
      #pragma unroll
      for (int j = 0; j < 4; j++)
        bfr[j] = *(const short8*)(Bs + (wq + j * 16 + fl) * LB + ks * 32 + fq * 8);
      #pragma unroll
      for (int i = 0; i < 2; i++)
        #pragma unroll
        for (int j = 0; j < 4; j++)
          acc[i][j] = __builtin_amdgcn_mfma_f32_16x16x32_bf16(afr[i], bfr[j], acc[i][j], 0, 0, 0);
    }
  }

  // entropy epilogue: reduce the 4 row-groups (lanes l^16, l^32) then across waves
  #pragma unroll
  for (int j = 0; j < 4; j++) {
    es4[j] += __shfl_xor(es4[j], 16);
    es4[j] += __shfl_xor(es4[j], 32);
    ets4[j] += __shfl_xor(ets4[j], 16);
    ets4[j] += __shfl_xor(ets4[j], 32);
  }
  if (lane < 16) {
    #pragma unroll
    for (int j = 0; j < 4; j++) {
      esh[wave * 64 + lane * 4 + j] = es4[j];
      esh[256 + wave * 64 + lane * 4 + j] = ets4[j];
    }
  }
  __syncthreads();
  if (t < 64) {
    const float Sx = esh[t] + esh[64 + t] + esh[128 + t] + esh[192 + t];
    const float Tx = esh[256 + t] + esh[320 + t] + esh[384 + t] + esh[448 + t];
    ent_v[(size_t)bb * N_ + n0 + t] = __logf(Sx) - Tx / Sx;
  }

  // S store: fragment-linear, 8x 16B per thread, fully coalesced
  float* sfrag = S + ((size_t)blockIdx.x * 256 + t) * 32;
  #pragma unroll
  for (int i = 0; i < 2; i++)
    #pragma unroll
    for (int j = 0; j < 4; j++)
      *(f32x4*)(sfrag + (i * 4 + j) * 4) = acc[i][j];
}

// ---------------- A2: block-local ve/te softmax + modulated softmax + PV ----------------
// S loaded fragment-linear (16B/lane); out written via LDS bounce -> float4 stores.
__global__ __launch_bounds__(256, 2) void attn_pv_kernel(
    const float* __restrict__ S,             // fragment-linear fp32
    const unsigned short* __restrict__ vT,   // [B][768][Q] bf16
    const float* __restrict__ ent_v,         // [B*4096]
    const float* __restrict__ ent_t,         // [B*128]
    const float* __restrict__ skq,           // [B*Q]
    float* __restrict__ out)                 // [B][768][4096]
{
  constexpr int LP = 136;
  constexpr int LN = 68;                    // out-bounce stride (272B rows, 16B-aligned)
  __shared__ unsigned short Ps[64 * LP];    // 17408 B
  __shared__ unsigned short Vs[64 * LP];    // 17408 B (aliased by Os)
  __shared__ float stats[2][64][2];         //  1024 B
  __shared__ float tesh[128];               //   512 B
  __shared__ float vesh[64];                //   256 B
  __shared__ float zred[4];
  __shared__ float zsum, tsum;
  float* Os = (float*)Vs;                   // 64*68*4 = 17408 B exactly

  const int bb = blockIdx.x >> 6;
  const int n0 = (blockIdx.x & 63) * 64;
  const int t = threadIdx.x;
  const int wave = t >> 6, lane = t & 63;
  const int fl = lane & 15, fq = lane >> 4;
  const int wm = (wave & 1) * 32;   // token half
  const int wq = (wave >> 1) * 64;  // q half

  // ---- block-local ve/te normalizers (no-max form, ent ~ 7, fp32-safe) ----
  const float* evb = ent_v + (size_t)bb * N_;
  float zp = 0.f;
  #pragma unroll
  for (int i = 0; i < 16; i++) zp += __expf(evb[t + 256 * i]);
  #pragma unroll
  for (int off = 32; off; off >>= 1) zp += __shfl_xor(zp, off);
  if (lane == 0) zred[wave] = zp;
  if (t < 128) tesh[t] = __expf(ent_t[bb * 128 + t]);
  if (t < 64) vesh[t] = __expf(evb[n0 + t]);
  __syncthreads();
  if (t == 0) zsum = zred[0] + zred[1] + zred[2] + zred[3];
  if (t < 64) {
    float s = tesh[t] + tesh[t + 64];
    #pragma unroll
    for (int off = 32; off; off >>= 1) s += __shfl_xor(s, off);
    if (t == 0) tsum = s;
  }
  __syncthreads();
  const float rZ = 1.0f / zsum;
  const float rT = 1.0f / tsum;

  // S load: fragment-linear (bitwise-identical values to attn_s's acc)
  f32x4 acc[2][4];
  const float* sfrag = S + ((size_t)blockIdx.x * 256 + t) * 32;
  #pragma unroll
  for (int i = 0; i < 2; i++)
    #pragma unroll
    for (int j = 0; j < 4; j++)
      acc[i][j] = *(const f32x4*)(sfrag + (i * 4 + j) * 4);

  // ---------- softmax with entropy modulation ----------
  const float rsD = 0.03608439182435161f;  // 1/sqrt(768)
  float tev[4], skv[4];
  #pragma unroll
  for (int j = 0; j < 4; j++) {
    int q = wq + j * 16 + fl;
    tev[j] = tesh[q] * rT;
    skv[j] = skq[bb * Q_ + q];
  }
  float vev4[2][4];
  #pragma unroll
  for (int i = 0; i < 2; i++)
    #pragma unroll
    for (int r = 0; r < 4; r++)
      vev4[i][r] = vesh[wm + i * 16 + fq * 4 + r] * rZ;

  float rmax[2][4], rsum[2][4];
  #pragma unroll
  for (int i = 0; i < 2; i++)
    #pragma unroll
    for (int r = 0; r < 4; r++) rmax[i][r] = -__builtin_inff();
  #pragma unroll
  for (int i = 0; i < 2; i++)
    #pragma unroll
    for (int j = 0; j < 4; j++)
      #pragma unroll
      for (int r = 0; r < 4; r++) {
        float L = (acc[i][j][r] + skv[j]) * rsD * vev4[i][r] * tev[j];
        acc[i][j][r] = L;
        rmax[i][r] = fmaxf(rmax[i][r], L);
      }
  #pragma unroll
  for (int off = 1; off < 16; off <<= 1)
    #pragma unroll
    for (int i = 0; i < 2; i++)
      #pragma unroll
      for (int r = 0; r < 4; r++)
        rmax[i][r] = fmaxf(rmax[i][r], __shfl_xor(rmax[i][r], off));
  #pragma unroll
  for (int i = 0; i < 2; i++)
    #pragma unroll
    for (int r = 0; r < 4; r++) rsum[i][r] = 0.f;
  #pragma unroll
  for (int i = 0; i < 2; i++)
    #pragma unroll
    for (int j = 0; j < 4; j++)
      #pragma unroll
      for (int r = 0; r < 4; r++) {
        float e = __expf(acc[i][j][r] - rmax[i][r]);
        acc[i][j][r] = e;
        rsum[i][r] += e;
      }
  #pragma unroll
  for (int off = 1; off < 16; off <<= 1)
    #pragma unroll
    for (int i = 0; i < 2; i++)
      #pragma unroll
      for (int r = 0; r < 4; r++) rsum[i][r] += __shfl_xor(rsum[i][r], off);

  const int qh = wq >> 6;
  if (fl == 0) {
    #pragma unroll
    for (int i = 0; i < 2; i++)
      #pragma unroll
      for (int r = 0; r < 4; r++) {
        int m = wm + i * 16 + fq * 4 + r;
        stats[qh][m][0] = rmax[i][r];
        stats[qh][m][1] = rsum[i][r];
      }
  }
  __syncthreads();
  float fac[2][4];
  #pragma unroll
  for (int i = 0; i < 2; i++)
    #pragma unroll
    for (int r = 0; r < 4; r++) {
      int m = wm + i * 16 + fq * 4 + r;
      float M2 = stats[1 - qh][m][0], S2 = stats[1 - qh][m][1];
      float Mf = fmaxf(rmax[i][r], M2);
      float sf = rsum[i][r] * __expf(rmax[i][r] - Mf) + S2 * __expf(M2 - Mf);
      fac[i][r] = __expf(rmax[i][r] - Mf) / sf;
    }
  #pragma unroll
  for (int i = 0; i < 2; i++)
    #pragma unroll
    for (int j = 0; j < 4; j++)
      #pragma unroll
      for (int r = 0; r < 4; r++) {
        int m = wm + i * 16 + fq * 4 + r;
        int q = wq + j * 16 + fl;
        Ps[m * LP + q] = f2bf(acc[i][j][r] * fac[i][r]);
      }

  // ---------- phase B: O^T = vT * P^T, d-chunks of 64; out via LDS bounce ----------
  const int wd = (wave & 1) * 32;
  const int wm2 = (wave >> 1) * 32;
  for (int dc = 0; dc < 12; dc++) {
    __syncthreads();  // Ps ready (dc=0); prior-chunk Os reads done
    const unsigned short* vbase = vT + ((size_t)bb * D_ + dc * 64) * Q_;
    #pragma unroll
    for (int i = 0; i < 4; i++) {
      const int c = t + 256 * i;
      const int d = c >> 4, qc = (c & 15) * 8;
      *(uint4*)(Vs + d * LP + qc) = *(const uint4*)(vbase + (size_t)d * Q_ + qc);
    }
    __syncthreads();
    f32x4 acc2[2][2];
    #pragma unroll
    for (int i = 0; i < 2; i++)
      #pragma unroll
      for (int j = 0; j < 2; j++) acc2[i][j] = {0.f, 0.f, 0.f, 0.f};
    #pragma unroll
    for (int ks = 0; ks < 4; ks++) {
      short8 vfr[2], pfr[2];
      #pragma unroll
      for (int i = 0; i < 2; i++)
        vfr[i] = *(const short8*)(Vs + (wd + i * 16 + fl) * LP + ks * 32 + fq * 8);
      #pragma unroll
      for (int j = 0; j < 2; j++)
        pfr[j] = *(const short8*)(Ps + (wm2 + j * 16 + fl) * LP + ks * 32 + fq * 8);
      #pragma unroll
      for (int i = 0; i < 2; i++)
        #pragma unroll
        for (int j = 0; j < 2; j++)
          acc2[i][j] = __builtin_amdgcn_mfma_f32_16x16x32_bf16(vfr[i], pfr[j], acc2[i][j], 0, 0, 0);
    }
    __syncthreads();  // all waves' Vs reads complete before Os overwrite
    #pragma unroll
    for (int i = 0; i < 2; i++)
      #pragma unroll
      for (int j = 0; j < 2; j++) {
        int mm = wm2 + j * 16 + fl;
        #pragma unroll
        for (int r = 0; r < 4; r++) {
          int d = wd + i * 16 + fq * 4 + r;
          Os[d * LN + mm] = acc2[i][j][r];
        }
      }
    __syncthreads();
    float* obase = out + ((size_t)bb * D_ + dc * 64) * N_ + n0;
    #pragma unroll
    for (int i = 0; i < 4; i++) {
      const int c = t + 256 * i;
      const int d = c >> 4, cg = c & 15;
      *(float4*)(obase + (size_t)d * N_ + cg * 4) = *(const float4*)(Os + d * LN + cg * 4);
    }
  }
}

extern "C" void kernel_launch(void* const* d_in, const int* in_sizes, int n_in,
                              void* d_out, int out_size, void* d_ws, size_t ws_size,
                              hipStream_t stream) {
  const float* vis  = (const float*)d_in[0];
  const float* text = (const float*)d_in[1];
  const float* Wq   = (const float*)d_in[2];
  const float* bq   = (const float*)d_in[3];
  const float* Wk   = (const float*)d_in[4];
  const float* bk   = (const float*)d_in[5];
  const float* Wv   = (const float*)d_in[6];
  const float* bv   = (const float*)d_in[7];
  float* out = (float*)d_out;
  char* ws = (char*)d_ws;

  unsigned short* textb = (unsigned short*)(ws + 0);
  unsigned short* Wkb   = (unsigned short*)(ws + 3145728);
  unsigned short* Wvb   = (unsigned short*)(ws + 4325376);
  unsigned short* WqTb  = (unsigned short*)(ws + 5505024);
  unsigned short* kb    = (unsigned short*)(ws + 6684672);
  unsigned short* kqb   = (unsigned short*)(ws + 9830400);
  unsigned short* vTb   = (unsigned short*)(ws + 12976128);
  float* ent_t = (float*)(ws + 16121856);
  float* ent_v = (float*)(ws + 16138240);
  float* skq   = (float*)(ws + 16662528);
  float* Sbuf  = (float*)(ws + 16777216);   // 33,554,432 B -> total ws 50,331,648 B

  // 1. weight casts + Wq transpose + text cast/entropy
  prep_kernel<<<dim3(24, 24, 4), 256, 0, stream>>>(Wk, Wv, Wq, text,
                                                   Wkb, Wvb, WqTb, textb, ent_t);
  // 2. k = text@Wk^T + bk || vT = (text@Wv^T + bv)^T
  gemm_kvT_kernel<<<dim3(32, 24), 256, 0, stream>>>(textb, Wkb, bk, kb, Wvb, bv, vTb);
  // 3. kq = k@Wq || skq = k@bq
  gemm_kq_bias_kernel<<<dim3(32, 28), 256, 0, stream>>>(kb, WqTb, kqb, bq, skq);
  // 4. S = vf*kq^T + inline visual entropy (vis read exactly once)
  attn_s_kernel<<<1024, 256, 0, stream>>>(vis, kqb, Sbuf, ent_v);
  // 5. block-local ve/te softmax + modulated softmax + PV -> out
  attn_pv_kernel<<<1024, 256, 0, stream>>>(Sbuf, vTb, ent_v, ent_t, skq, out);
}

// Round 9
// 422.692 us; speedup vs baseline: 1.0360x; 1.0360x over previous
//
#include <hip/hip_runtime.h>

#define B_ 16
#define D_ 768
#define N_ 4096
#define Q_ 128

typedef __attribute__((ext_vector_type(4))) float f32x4;
typedef __attribute__((ext_vector_type(8))) short short8;
typedef __attribute__((ext_vector_type(4))) short sv4;

__device__ __forceinline__ unsigned short f2bf(float f) {
  union { float f; unsigned u; } x; x.f = f;
  unsigned u = x.u;
  unsigned r = u + 0x7fffu + ((u >> 16) & 1u);
  return (unsigned short)(r >> 16);
}
__device__ __forceinline__ float bf2f(unsigned short h) {
  union { unsigned u; float f; } x; x.u = ((unsigned)h) << 16;
  return x.f;
}

// ---- prep: z=0 cast Wk, z=1 cast Wv, z=2 transpose+cast Wq, z=3 text cast+entropy ----
__global__ __launch_bounds__(256) void prep_kernel(
    const float* __restrict__ Wk, const float* __restrict__ Wv,
    const float* __restrict__ Wq, const float* __restrict__ text,
    unsigned short* __restrict__ Wkb, unsigned short* __restrict__ Wvb,
    unsigned short* __restrict__ WqTb, unsigned short* __restrict__ textb,
    float* __restrict__ ent_t) {
  __shared__ float tile[32][33];
  const int z = blockIdx.z;
  const int t = threadIdx.x;
  if (z <= 1) {
    const float* src = z ? Wv : Wk;
    unsigned short* dst = z ? Wvb : Wkb;
    int i = (blockIdx.y * 24 + blockIdx.x) * 256 + t;  // 576*256 = 768*768/4
    float4 v = ((const float4*)src)[i];
    ushort4 o;
    o.x = f2bf(v.x); o.y = f2bf(v.y); o.z = f2bf(v.z); o.w = f2bf(v.w);
    ((ushort4*)dst)[i] = o;
  } else if (z == 2) {
    int bx = blockIdx.x * 32, by = blockIdx.y * 32;
    int tx = t & 31, ty = t >> 5;
    #pragma unroll
    for (int i = 0; i < 32; i += 8)
      tile[ty + i][tx] = Wq[(size_t)(by + ty + i) * D_ + bx + tx];
    __syncthreads();
    #pragma unroll
    for (int i = 0; i < 32; i += 8)
      WqTb[(size_t)(bx + ty + i) * D_ + by + tx] = f2bf(tile[tx][ty + i]);
  } else {
    // text: cast fp32->bf16 + per-row softmax-entropy; 512 of 576 blocks used
    int idx = blockIdx.y * 24 + blockIdx.x;
    if (idx >= 512) return;
    int row = idx * 4 + (t >> 6);
    int lane = t & 63;
    const float4* src = (const float4*)(text + (size_t)row * D_);
    ushort4* dst = (ushort4*)(textb + (size_t)row * D_);
    float s = 0.f, tt = 0.f;
    #pragma unroll
    for (int j = 0; j < 3; j++) {
      float4 v = src[lane + 64 * j];
      float e0 = __expf(v.x), e1 = __expf(v.y), e2 = __expf(v.z), e3 = __expf(v.w);
      s += (e0 + e1) + (e2 + e3);
      tt += v.x * e0 + v.y * e1;
      tt += v.z * e2 + v.w * e3;
      ushort4 o;
      o.x = f2bf(v.x); o.y = f2bf(v.y); o.z = f2bf(v.z); o.w = f2bf(v.w);
      dst[lane + 64 * j] = o;
    }
    #pragma unroll
    for (int off = 32; off; off >>= 1) {
      s += __shfl_xor(s, off);
      tt += __shfl_xor(tt, off);
    }
    if (lane == 0) ent_t[row] = __logf(s) - tt / s;  // m + log(sum e^{x-m}) - E_p[x]
  }
}

// ---------------- merged k (+bk) and vT (+bv, transposed store) GEMM --------------------
__global__ __launch_bounds__(256) void gemm_kvT_kernel(
    const unsigned short* __restrict__ A, const unsigned short* __restrict__ Wkb,
    const float* __restrict__ bk, unsigned short* __restrict__ kb,
    const unsigned short* __restrict__ Wvb, const float* __restrict__ bv,
    unsigned short* __restrict__ vTb) {
  constexpr int LDA = 72;
  __shared__ unsigned short As[64 * LDA];
  __shared__ unsigned short Bs[64 * LDA];
  const bool isV = blockIdx.y >= 12;
  const unsigned short* Bm = isV ? Wvb : Wkb;
  const float* bias = isV ? bv : bk;
  unsigned short* C = isV ? vTb : kb;
  int m0 = blockIdx.x * 64, n0 = (isV ? blockIdx.y - 12 : blockIdx.y) * 64;
  int t = threadIdx.x, wave = t >> 6, lane = t & 63;
  int wm = (wave & 1) * 32, wn = (wave >> 1) * 32;
  int fl = lane & 15, fq = lane >> 4;
  f32x4 acc[2][2];
  #pragma unroll
  for (int i = 0; i < 2; i++)
    #pragma unroll
    for (int j = 0; j < 2; j++) acc[i][j] = {0.f, 0.f, 0.f, 0.f};
  for (int k0 = 0; k0 < D_; k0 += 64) {
    __syncthreads();
    #pragma unroll
    for (int i = 0; i < 2; i++) {
      int c = t + 256 * i;
      int sr = c >> 3, sc = (c & 7) * 8;
      *(uint4*)(As + sr * LDA + sc) = *(const uint4*)(A + (size_t)(m0 + sr) * D_ + k0 + sc);
      *(uint4*)(Bs + sr * LDA + sc) = *(const uint4*)(Bm + (size_t)(n0 + sr) * D_ + k0 + sc);
    }
    __syncthreads();
    #pragma unroll
    for (int ks = 0; ks < 2; ks++) {
      short8 afr[2], bfr[2];
      #pragma unroll
      for (int i = 0; i < 2; i++)
        afr[i] = *(const short8*)(As + (wm + i * 16 + fl) * LDA + ks * 32 + fq * 8);
      #pragma unroll
      for (int j = 0; j < 2; j++)
        bfr[j] = *(const short8*)(Bs + (wn + j * 16 + fl) * LDA + ks * 32 + fq * 8);
      #pragma unroll
      for (int i = 0; i < 2; i++)
        #pragma unroll
        for (int j = 0; j < 2; j++)
          acc[i][j] = __builtin_amdgcn_mfma_f32_16x16x32_bf16(afr[i], bfr[j], acc[i][j], 0, 0, 0);
    }
  }
  #pragma unroll
  for (int i = 0; i < 2; i++)
    #pragma unroll
    for (int j = 0; j < 2; j++) {
      int n = n0 + wn + j * 16 + fl;
      float bb = bias[n];
      #pragma unroll
      for (int r = 0; r < 4; r++) {
        int m = m0 + wm + i * 16 + fq * 4 + r;
        float val = acc[i][j][r] + bb;
        if (isV) {
          int bt = m >> 7, q = m & 127;
          C[((size_t)bt * D_ + n) * Q_ + q] = f2bf(val);
        } else {
          C[(size_t)m * D_ + n] = f2bf(val);
        }
      }
    }
}

// ---------------- merged kq GEMM (y<12) and skq bias_dot (y>=12) ------------------------
__global__ __launch_bounds__(256) void gemm_kq_bias_kernel(
    const unsigned short* __restrict__ kb, const unsigned short* __restrict__ WqTb,
    unsigned short* __restrict__ kqb, const float* __restrict__ bq,
    float* __restrict__ skq) {
  constexpr int LDA = 72;
  __shared__ unsigned short As[64 * LDA];
  __shared__ unsigned short Bs[64 * LDA];
  const int t = threadIdx.x;
  if (blockIdx.y >= 12) {
    int idx = (blockIdx.y - 12) * 32 + blockIdx.x;   // 0..511
    int row = idx * 4 + (t >> 6);
    int lane = t & 63;
    const unsigned short* kr = kb + (size_t)row * D_;
    float s = 0.f;
    for (int k = lane; k < D_; k += 64) s += bq[k] * bf2f(kr[k]);
    #pragma unroll
    for (int off = 32; off; off >>= 1) s += __shfl_xor(s, off);
    if (lane == 0) skq[row] = s;
    return;
  }
  int m0 = blockIdx.x * 64, n0 = blockIdx.y * 64;
  int wave = t >> 6, lane = t & 63;
  int wm = (wave & 1) * 32, wn = (wave >> 1) * 32;
  int fl = lane & 15, fq = lane >> 4;
  f32x4 acc[2][2];
  #pragma unroll
  for (int i = 0; i < 2; i++)
    #pragma unroll
    for (int j = 0; j < 2; j++) acc[i][j] = {0.f, 0.f, 0.f, 0.f};
  for (int k0 = 0; k0 < D_; k0 += 64) {
    __syncthreads();
    #pragma unroll
    for (int i = 0; i < 2; i++) {
      int c = t + 256 * i;
      int sr = c >> 3, sc = (c & 7) * 8;
      *(uint4*)(As + sr * LDA + sc) = *(const uint4*)(kb + (size_t)(m0 + sr) * D_ + k0 + sc);
      *(uint4*)(Bs + sr * LDA + sc) = *(const uint4*)(WqTb + (size_t)(n0 + sr) * D_ + k0 + sc);
    }
    __syncthreads();
    #pragma unroll
    for (int ks = 0; ks < 2; ks++) {
      short8 afr[2], bfr[2];
      #pragma unroll
      for (int i = 0; i < 2; i++)
        afr[i] = *(const short8*)(As + (wm + i * 16 + fl) * LDA + ks * 32 + fq * 8);
      #pragma unroll
      for (int j = 0; j < 2; j++)
        bfr[j] = *(const short8*)(Bs + (wn + j * 16 + fl) * LDA + ks * 32 + fq * 8);
      #pragma unroll
      for (int i = 0; i < 2; i++)
        #pragma unroll
        for (int j = 0; j < 2; j++)
          acc[i][j] = __builtin_amdgcn_mfma_f32_16x16x32_bf16(afr[i], bfr[j], acc[i][j], 0, 0, 0);
    }
  }
  #pragma unroll
  for (int i = 0; i < 2; i++)
    #pragma unroll
    for (int j = 0; j < 2; j++) {
      int n = n0 + wn + j * 16 + fl;
      #pragma unroll
      for (int r = 0; r < 4; r++) {
        int m = m0 + wm + i * 16 + fq * 4 + r;
        kqb[(size_t)m * D_ + n] = f2bf(acc[i][j][r]);
      }
    }
}

// ---------------- A1: S = vf*kq^T (bf16 fragment-planar) + inline visual entropy --------
// R7-verbatim staging/MFMA/entropy; only the S store changed: bf16, layout
// [block][frag 8][thread 256][4] -> ushort4 (8B/lane) fully coalesced per plane.
__global__ __launch_bounds__(256, 2) void attn_s_kernel(
    const float* __restrict__ vis,
    const unsigned short* __restrict__ kq,   // [B][Q][768] bf16
    unsigned short* __restrict__ S,          // [1024][8][256][4] bf16
    float* __restrict__ ent_v)               // [B][4096]
{
  constexpr int LA = 68;
  constexpr int LB = 72;
  __shared__ unsigned short As[64 * LA];    //  8704 B
  __shared__ unsigned short Bs[128 * LB];   // 18432 B
  __shared__ float esh[512];                //  2048 B

  const int bb = blockIdx.x >> 6;
  const int n0 = (blockIdx.x & 63) * 64;
  const int t = threadIdx.x;
  const int wave = t >> 6, lane = t & 63;
  const int fl = lane & 15, fq = lane >> 4;
  const int wm = (wave & 1) * 32;   // token half (32 of 64)
  const int wq = (wave >> 1) * 64;  // q half

  const float* abase = vis + (size_t)bb * D_ * N_ + n0;
  const unsigned short* bbase = kq + (size_t)bb * Q_ * D_;

  f32x4 acc[2][4];
  #pragma unroll
  for (int i = 0; i < 2; i++)
    #pragma unroll
    for (int j = 0; j < 4; j++) acc[i][j] = {0.f, 0.f, 0.f, 0.f};

  const int smi = t & 63;   // token within block
  const int ph = t >> 6;    // k-quarter
  float es = 0.f, ets = 0.f;  // online softmax-entropy (no-max; fp32-safe for |v|<~6)

  for (int k0 = 0; k0 < D_; k0 += 64) {
    __syncthreads();
    #pragma unroll
    for (int i = 0; i < 8; i++) {
      const int kk = 2 * (ph + 4 * i);
      const float v0 = abase[(size_t)(k0 + kk) * N_ + smi];
      const float v1 = abase[(size_t)(k0 + kk + 1) * N_ + smi];
      const float e0 = __expf(v0), e1 = __expf(v1);
      es += e0 + e1;
      ets += v0 * e0 + v1 * e1;
      const unsigned pk = (unsigned)f2bf(v0) | ((unsigned)f2bf(v1) << 16);
      *(unsigned*)(As + smi * LA + kk) = pk;
    }
    #pragma unroll
    for (int i = 0; i < 4; i++) {
      const int c = t + 256 * i;
      const int q = c >> 3, kc = (c & 7) * 8;
      const uint4 v = *(const uint4*)(bbase + (size_t)q * D_ + k0 + kc);
      *(uint4*)(Bs + q * LB + kc) = v;
    }
    __syncthreads();
    #pragma unroll
    for (int ks = 0; ks < 2; ks++) {
      short8 afr[2], bfr[4];
      #pragma unroll
      for (int i = 0; i < 2; i++) {
        const unsigned short* pa = As + (wm + i * 16 + fl) * LA + ks * 32 + fq * 8;
        sv4 lo = *(const sv4*)pa;
        sv4 hi = *(const sv4*)(pa + 4);
        afr[i] = __builtin_shufflevector(lo, hi, 0, 1, 2, 3, 4, 5, 6, 7);
      }
      #pragma unroll
      for (int j = 0; j < 4; j++)
        bfr[j] = *(const short8*)(Bs + (wq + j * 16 + fl) * LB + ks * 32 + fq * 8);
      #pragma unroll
      for (int i = 0; i < 2; i++)
        #pragma unroll
        for (int j = 0; j < 4; j++)
          acc[i][j] = __builtin_amdgcn_mfma_f32_16x16x32_bf16(afr[i], bfr[j], acc[i][j], 0, 0, 0);
    }
  }

  // entropy epilogue: 4 threads (k-quarters) per token
  esh[t] = es;
  esh[256 + t] = ets;
  __syncthreads();
  if (t < 64) {
    const float Sx = esh[t] + esh[t + 64] + esh[t + 128] + esh[t + 192];
    const float Tx = esh[256 + t] + esh[320 + t] + esh[384 + t] + esh[448 + t];
    ent_v[(size_t)bb * N_ + n0 + t] = __logf(Sx) - Tx / Sx;
  }

  // S store: bf16 fragment-planar, ushort4 (8B) per fragment plane, coalesced
  unsigned short* sfrag = S + (size_t)blockIdx.x * 8192 + t * 4;
  #pragma unroll
  for (int i = 0; i < 2; i++)
    #pragma unroll
    for (int j = 0; j < 4; j++) {
      ushort4 o;
      o.x = f2bf(acc[i][j][0]); o.y = f2bf(acc[i][j][1]);
      o.z = f2bf(acc[i][j][2]); o.w = f2bf(acc[i][j][3]);
      *(ushort4*)(sfrag + (i * 4 + j) * 1024) = o;
    }
}

// ---------------- A2: block-local ve/te softmax + modulated softmax + PV ----------------
// R7-verbatim except the S load: bf16 fragment-planar.
__global__ __launch_bounds__(256, 2) void attn_pv_kernel(
    const unsigned short* __restrict__ S,    // [1024][8][256][4] bf16
    const unsigned short* __restrict__ vT,   // [B][768][Q] bf16
    const float* __restrict__ ent_v,         // [B*4096]
    const float* __restrict__ ent_t,         // [B*128]
    const float* __restrict__ skq,           // [B*Q]
    float* __restrict__ out)                 // [B][768][4096]
{
  constexpr int LP = 136;
  __shared__ unsigned short Ps[64 * LP];    // 17408 B
  __shared__ unsigned short Vs[64 * LP];    // 17408 B
  __shared__ float stats[2][64][2];         //  1024 B
  __shared__ float tesh[128];               //   512 B
  __shared__ float vesh[64];                //   256 B
  __shared__ float zred[4];
  __shared__ float zsum, tsum;

  const int bb = blockIdx.x >> 6;
  const int n0 = (blockIdx.x & 63) * 64;
  const int t = threadIdx.x;
  const int wave = t >> 6, lane = t & 63;
  const int fl = lane & 15, fq = lane >> 4;
  const int wm = (wave & 1) * 32;   // token half
  const int wq = (wave >> 1) * 64;  // q half

  // ---- block-local ve/te normalizers (no-max form, ent ~ 7, fp32-safe) ----
  const float* evb = ent_v + (size_t)bb * N_;
  float zp = 0.f;
  #pragma unroll
  for (int i = 0; i < 16; i++) zp += __expf(evb[t + 256 * i]);
  #pragma unroll
  for (int off = 32; off; off >>= 1) zp += __shfl_xor(zp, off);
  if (lane == 0) zred[wave] = zp;
  if (t < 128) tesh[t] = __expf(ent_t[bb * 128 + t]);
  if (t < 64) vesh[t] = __expf(evb[n0 + t]);
  __syncthreads();
  if (t == 0) zsum = zred[0] + zred[1] + zred[2] + zred[3];
  if (t < 64) {
    float s = tesh[t] + tesh[t + 64];
    #pragma unroll
    for (int off = 32; off; off >>= 1) s += __shfl_xor(s, off);
    if (t == 0) tsum = s;
  }
  __syncthreads();
  const float rZ = 1.0f / zsum;
  const float rT = 1.0f / tsum;

  // S load: bf16 fragment-planar (same mapping as attn_s store)
  f32x4 acc[2][4];
  const unsigned short* sfrag = S + (size_t)blockIdx.x * 8192 + t * 4;
  #pragma unroll
  for (int i = 0; i < 2; i++)
    #pragma unroll
    for (int j = 0; j < 4; j++) {
      const ushort4 v = *(const ushort4*)(sfrag + (i * 4 + j) * 1024);
      acc[i][j] = {bf2f(v.x), bf2f(v.y), bf2f(v.z), bf2f(v.w)};
    }

  // ---------- softmax with entropy modulation ----------
  const float rsD = 0.03608439182435161f;  // 1/sqrt(768)
  float tev[4], skv[4];
  #pragma unroll
  for (int j = 0; j < 4; j++) {
    int q = wq + j * 16 + fl;
    tev[j] = tesh[q] * rT;
    skv[j] = skq[bb * Q_ + q];
  }
  float vev4[2][4];
  #pragma unroll
  for (int i = 0; i < 2; i++)
    #pragma unroll
    for (int r = 0; r < 4; r++)
      vev4[i][r] = vesh[wm + i * 16 + fq * 4 + r] * rZ;

  float rmax[2][4], rsum[2][4];
  #pragma unroll
  for (int i = 0; i < 2; i++)
    #pragma unroll
    for (int r = 0; r < 4; r++) rmax[i][r] = -__builtin_inff();
  #pragma unroll
  for (int i = 0; i < 2; i++)
    #pragma unroll
    for (int j = 0; j < 4; j++)
      #pragma unroll
      for (int r = 0; r < 4; r++) {
        float L = (acc[i][j][r] + skv[j]) * rsD * vev4[i][r] * tev[j];
        acc[i][j][r] = L;
        rmax[i][r] = fmaxf(rmax[i][r], L);
      }
  #pragma unroll
  for (int off = 1; off < 16; off <<= 1)
    #pragma unroll
    for (int i = 0; i < 2; i++)
      #pragma unroll
      for (int r = 0; r < 4; r++)
        rmax[i][r] = fmaxf(rmax[i][r], __shfl_xor(rmax[i][r], off));
  #pragma unroll
  for (int i = 0; i < 2; i++)
    #pragma unroll
    for (int r = 0; r < 4; r++) rsum[i][r] = 0.f;
  #pragma unroll
  for (int i = 0; i < 2; i++)
    #pragma unroll
    for (int j = 0; j < 4; j++)
      #pragma unroll
      for (int r = 0; r < 4; r++) {
        float e = __expf(acc[i][j][r] - rmax[i][r]);
        acc[i][j][r] = e;
        rsum[i][r] += e;
      }
  #pragma unroll
  for (int off = 1; off < 16; off <<= 1)
    #pragma unroll
    for (int i = 0; i < 2; i++)
      #pragma unroll
      for (int r = 0; r < 4; r++) rsum[i][r] += __shfl_xor(rsum[i][r], off);

  const int qh = wq >> 6;
  if (fl == 0) {
    #pragma unroll
    for (int i = 0; i < 2; i++)
      #pragma unroll
      for (int r = 0; r < 4; r++) {
        int m = wm + i * 16 + fq * 4 + r;
        stats[qh][m][0] = rmax[i][r];
        stats[qh][m][1] = rsum[i][r];
      }
  }
  __syncthreads();
  float fac[2][4];
  #pragma unroll
  for (int i = 0; i < 2; i++)
    #pragma unroll
    for (int r = 0; r < 4; r++) {
      int m = wm + i * 16 + fq * 4 + r;
      float M2 = stats[1 - qh][m][0], S2 = stats[1 - qh][m][1];
      float Mf = fmaxf(rmax[i][r], M2);
      float sf = rsum[i][r] * __expf(rmax[i][r] - Mf) + S2 * __expf(M2 - Mf);
      fac[i][r] = __expf(rmax[i][r] - Mf) / sf;
    }
  #pragma unroll
  for (int i = 0; i < 2; i++)
    #pragma unroll
    for (int j = 0; j < 4; j++)
      #pragma unroll
      for (int r = 0; r < 4; r++) {
        int m = wm + i * 16 + fq * 4 + r;
        int q = wq + j * 16 + fl;
        Ps[m * LP + q] = f2bf(acc[i][j][r] * fac[i][r]);
      }

  // ---------- phase B: O^T = vT * P^T, d-chunks of 64 (12 chunks) ----------
  const int wd = (wave & 1) * 32;
  const int wm2 = (wave >> 1) * 32;
  for (int dc = 0; dc < 12; dc++) {
    __syncthreads();
    const unsigned short* vbase = vT + ((size_t)bb * D_ + dc * 64) * Q_;
    #pragma unroll
    for (int i = 0; i < 4; i++) {
      const int c = t + 256 * i;
      const int d = c >> 4, qc = (c & 15) * 8;
      *(uint4*)(Vs + d * LP + qc) = *(const uint4*)(vbase + (size_t)d * Q_ + qc);
    }
    __syncthreads();
    f32x4 acc2[2][2];
    #pragma unroll
    for (int i = 0; i < 2; i++)
      #pragma unroll
      for (int j = 0; j < 2; j++) acc2[i][j] = {0.f, 0.f, 0.f, 0.f};
    #pragma unroll
    for (int ks = 0; ks < 4; ks++) {
      short8 vfr[2], pfr[2];
      #pragma unroll
      for (int i = 0; i < 2; i++)
        vfr[i] = *(const short8*)(Vs + (wd + i * 16 + fl) * LP + ks * 32 + fq * 8);
      #pragma unroll
      for (int j = 0; j < 2; j++)
        pfr[j] = *(const short8*)(Ps + (wm2 + j * 16 + fl) * LP + ks * 32 + fq * 8);
      #pragma unroll
      for (int i = 0; i < 2; i++)
        #pragma unroll
        for (int j = 0; j < 2; j++)
          acc2[i][j] = __builtin_amdgcn_mfma_f32_16x16x32_bf16(vfr[i], pfr[j], acc2[i][j], 0, 0, 0);
    }
    float* obase = out + ((size_t)bb * D_ + dc * 64) * N_ + n0;
    #pragma unroll
    for (int i = 0; i < 2; i++)
      #pragma unroll
      for (int j = 0; j < 2; j++) {
        int mm = wm2 + j * 16 + fl;
        #pragma unroll
        for (int r = 0; r < 4; r++) {
          int d = wd + i * 16 + fq * 4 + r;
          obase[(size_t)d * N_ + mm] = acc2[i][j][r];
        }
      }
  }
}

extern "C" void kernel_launch(void* const* d_in, const int* in_sizes, int n_in,
                              void* d_out, int out_size, void* d_ws, size_t ws_size,
                              hipStream_t stream) {
  const float* vis  = (const float*)d_in[0];
  const float* text = (const float*)d_in[1];
  const float* Wq   = (const float*)d_in[2];
  const float* bq   = (const float*)d_in[3];
  const float* Wk   = (const float*)d_in[4];
  const float* bk   = (const float*)d_in[5];
  const float* Wv   = (const float*)d_in[6];
  const float* bv   = (const float*)d_in[7];
  float* out = (float*)d_out;
  char* ws = (char*)d_ws;

  unsigned short* textb = (unsigned short*)(ws + 0);
  unsigned short* Wkb   = (unsigned short*)(ws + 3145728);
  unsigned short* Wvb   = (unsigned short*)(ws + 4325376);
  unsigned short* WqTb  = (unsigned short*)(ws + 5505024);
  unsigned short* kb    = (unsigned short*)(ws + 6684672);
  unsigned short* kqb   = (unsigned short*)(ws + 9830400);
  unsigned short* vTb   = (unsigned short*)(ws + 12976128);
  float* ent_t = (float*)(ws + 16121856);
  float* ent_v = (float*)(ws + 16138240);
  float* skq   = (float*)(ws + 16662528);
  unsigned short* Sbuf = (unsigned short*)(ws + 16777216);  // 16,777,216 B (bf16)

  // 1. weight casts + Wq transpose + text cast/entropy
  prep_kernel<<<dim3(24, 24, 4), 256, 0, stream>>>(Wk, Wv, Wq, text,
                                                   Wkb, Wvb, WqTb, textb, ent_t);
  // 2. k = text@Wk^T + bk || vT = (text@Wv^T + bv)^T
  gemm_kvT_kernel<<<dim3(32, 24), 256, 0, stream>>>(textb, Wkb, bk, kb, Wvb, bv, vTb);
  // 3. kq = k@Wq || skq = k@bq
  gemm_kq_bias_kernel<<<dim3(32, 28), 256, 0, stream>>>(kb, WqTb, kqb, bq, skq);
  // 4. S = vf*kq^T (bf16) + inline visual entropy (vis read exactly once)
  attn_s_kernel<<<1024, 256, 0, stream>>>(vis, kqb, Sbuf, ent_v);
  // 5. block-local ve/te softmax + modulated softmax + PV -> out
  attn_pv_kernel<<<1024, 256, 0, stream>>>(Sbuf, vTb, ent_v, ent_t, skq, out);
}